// Round 1
// baseline (275.082 us; speedup 1.0000x reference)
//
#include <hip/hip_runtime.h>
#include <hip/hip_bf16.h>

#define T_ 4096
#define C_ 1024
#define H_ 64
#define LSTR 72  // LDS row stride (elems): mult of 8 keeps ds_read_b128 16B-aligned, breaks pow2 banks

typedef short bf16x8 __attribute__((ext_vector_type(8)));
typedef float f32x4 __attribute__((ext_vector_type(4)));

__device__ __forceinline__ short f2bf(float f) {
  union { __hip_bfloat16 h; short s; } u;
  u.h = __float2bfloat16(f);
  return u.s;
}

// ---- kernel 0: W[c][h] fp32 -> Wt[n][c] bf16, n in [0,192): 0-63=K, 64-127=Q, 128-191=V
__global__ void wtrans_kernel(const float* __restrict__ Wk,
                              const float* __restrict__ Wq,
                              const float* __restrict__ Wv,
                              __hip_bfloat16* __restrict__ Wt) {
  int tid = blockIdx.x * 256 + threadIdx.x;
  if (tid >= 192 * 1024) return;
  int n = tid >> 10;
  int c = tid & 1023;
  const float* W = (n < 64) ? Wk : ((n < 128) ? Wq : Wv);
  Wt[tid] = __float2bfloat16(W[c * 64 + (n & 63)]);
}

// ---- kernel 1: qkv projection. 1024 wave-jobs of 16 rows x 192 cols, K=1024.
__global__ __launch_bounds__(256) void proj_kernel(
    const float* __restrict__ x, const __hip_bfloat16* __restrict__ Wt,
    __hip_bfloat16* __restrict__ qb, __hip_bfloat16* __restrict__ kb,
    __hip_bfloat16* __restrict__ vT) {
  __shared__ __hip_bfloat16 vlds[4][64 * 16];
  const int lane = threadIdx.x & 63;
  const int wave = threadIdx.x >> 6;
  const int m = lane & 15;
  const int quad = lane >> 4;
  const int t0 = (blockIdx.x * 4 + wave) * 16;

  f32x4 acc[12];
#pragma unroll
  for (int i = 0; i < 12; ++i) acc[i] = (f32x4){0.f, 0.f, 0.f, 0.f};

  const float* xrow = x + (size_t)(t0 + m) * C_ + quad * 8;
  const __hip_bfloat16* wrow = Wt + (size_t)m * C_ + quad * 8;

  for (int kc = 0; kc < C_; kc += 32) {
    float4 xa = *(const float4*)(xrow + kc);
    float4 xb = *(const float4*)(xrow + kc + 4);
    bf16x8 a;
    a[0] = f2bf(xa.x); a[1] = f2bf(xa.y); a[2] = f2bf(xa.z); a[3] = f2bf(xa.w);
    a[4] = f2bf(xb.x); a[5] = f2bf(xb.y); a[6] = f2bf(xb.z); a[7] = f2bf(xb.w);
#pragma unroll
    for (int nt = 0; nt < 12; ++nt) {
      bf16x8 bfrag = *(const bf16x8*)(wrow + (size_t)nt * 16 * C_ + kc);
      acc[nt] = __builtin_amdgcn_mfma_f32_16x16x32_bf16(a, bfrag, acc[nt], 0, 0, 0);
    }
  }

  // k (acc 0..3), q (acc 4..7): C-layout row=quad*4+r, col=nt*16+m
#pragma unroll
  for (int nt = 0; nt < 4; ++nt) {
#pragma unroll
    for (int r = 0; r < 4; ++r) {
      size_t row = (size_t)(t0 + quad * 4 + r);
      int col = nt * 16 + m;
      kb[row * H_ + col] = __float2bfloat16(acc[nt][r]);
      qb[row * H_ + col] = __float2bfloat16(acc[4 + nt][r]);
    }
  }
  // v (acc 8..11): transpose to vT[b][h][t] via wave-private LDS
  __hip_bfloat16* vl = &vlds[wave][0];
#pragma unroll
  for (int nt = 0; nt < 4; ++nt)
#pragma unroll
    for (int r = 0; r < 4; ++r)
      vl[(nt * 16 + m) * 16 + quad * 4 + r] = __float2bfloat16(acc[8 + nt][r]);
  __syncthreads();
  int bb = t0 >> 12;
  int tl = t0 & (T_ - 1);
  uint4 v0 = *(const uint4*)(vl + lane * 16);
  uint4 v1 = *(const uint4*)(vl + lane * 16 + 8);
  __hip_bfloat16* dst = vT + ((size_t)bb * H_ + lane) * T_ + tl;
  *(uint4*)(dst) = v0;
  *(uint4*)(dst + 8) = v1;
}

// ---- kernel 2: causal flash attention. Grid (64 qblocks, 4 batches), 4 waves/WG.
__global__ __launch_bounds__(256) void flash_kernel(
    const __hip_bfloat16* __restrict__ qb, const __hip_bfloat16* __restrict__ kb,
    const __hip_bfloat16* __restrict__ vT, float* __restrict__ out) {
  __shared__ __hip_bfloat16 Kl[64 * LSTR];        // [kv_t][h]
  __shared__ __hip_bfloat16 Vl[64 * LSTR];        // [h][kv_t]  (pre-transposed v)
  __shared__ __hip_bfloat16 Pl[4][16 * LSTR];     // per-wave P round-trip C->A layout

  const int qblk = blockIdx.x;
  const int b = blockIdx.y;
  const int q0 = qblk * 64;
  const int tid = threadIdx.x;
  const int lane = tid & 63;
  const int wave = tid >> 6;
  const int m = lane & 15;
  const int quad = lane >> 4;

  // Q A-frags direct from global: A[m=lane&15][k=quad*8+j]
  const __hip_bfloat16* qbase = qb + ((size_t)b * T_ + q0 + wave * 16 + m) * H_;
  bf16x8 qf0 = *(const bf16x8*)(qbase + quad * 8);
  bf16x8 qf1 = *(const bf16x8*)(qbase + 32 + quad * 8);

  f32x4 Oacc[4];
#pragma unroll
  for (int i = 0; i < 4; ++i) Oacc[i] = (f32x4){0.f, 0.f, 0.f, 0.f};
  float mrow[4], lrow[4];
#pragma unroll
  for (int r = 0; r < 4; ++r) { mrow[r] = -__builtin_inff(); lrow[r] = 0.f; }

  const int srow = tid >> 2;
  const int scol = (tid & 3) * 16;
  const __hip_bfloat16* kg = kb + (size_t)b * T_ * H_;
  const __hip_bfloat16* vg = vT + (size_t)b * H_ * T_;
  const float cscale = 0.18033688011112042f;  // log2(e)/sqrt(64)
  __hip_bfloat16* Plw = &Pl[wave][0];

  for (int kt = 0; kt <= qblk; ++kt) {
    const __hip_bfloat16* ksrc = kg + (size_t)(kt * 64 + srow) * H_ + scol;
    uint4 k0 = *(const uint4*)(ksrc);
    uint4 k1 = *(const uint4*)(ksrc + 8);
    const __hip_bfloat16* vsrc = vg + (size_t)srow * T_ + kt * 64 + scol;
    uint4 v0 = *(const uint4*)(vsrc);
    uint4 v1 = *(const uint4*)(vsrc + 8);
    __syncthreads();  // previous iteration's readers done
    *(uint4*)(&Kl[srow * LSTR + scol]) = k0;
    *(uint4*)(&Kl[srow * LSTR + scol + 8]) = k1;
    *(uint4*)(&Vl[srow * LSTR + scol]) = v0;
    *(uint4*)(&Vl[srow * LSTR + scol + 8]) = v1;
    __syncthreads();

    // S = Q K^T : B-frag B[k][n]=K[n][k] -> row n of Kl, k-contiguous
    f32x4 s[4];
#pragma unroll
    for (int nt = 0; nt < 4; ++nt) s[nt] = (f32x4){0.f, 0.f, 0.f, 0.f};
#pragma unroll
    for (int nt = 0; nt < 4; ++nt) {
      bf16x8 kf0 = *(const bf16x8*)(&Kl[(nt * 16 + m) * LSTR + quad * 8]);
      bf16x8 kf1 = *(const bf16x8*)(&Kl[(nt * 16 + m) * LSTR + 32 + quad * 8]);
      s[nt] = __builtin_amdgcn_mfma_f32_16x16x32_bf16(qf0, kf0, s[nt], 0, 0, 0);
      s[nt] = __builtin_amdgcn_mfma_f32_16x16x32_bf16(qf1, kf1, s[nt], 0, 0, 0);
    }

    // scale into exp2 domain + causal mask on diagonal tile
    float xs[4][4];
#pragma unroll
    for (int nt = 0; nt < 4; ++nt)
#pragma unroll
      for (int r = 0; r < 4; ++r) {
        float xv = s[nt][r] * cscale;
        if (kt == qblk && (nt * 16 + m) > (wave * 16 + quad * 4 + r))
          xv = -__builtin_inff();
        xs[nt][r] = xv;
      }

    // online softmax: row stats across the 16 lanes sharing a row (xor bits 0..3)
    float mnew[4], alpha[4];
#pragma unroll
    for (int r = 0; r < 4; ++r) {
      float v = fmaxf(fmaxf(xs[0][r], xs[1][r]), fmaxf(xs[2][r], xs[3][r]));
      v = fmaxf(v, __shfl_xor(v, 1));
      v = fmaxf(v, __shfl_xor(v, 2));
      v = fmaxf(v, __shfl_xor(v, 4));
      v = fmaxf(v, __shfl_xor(v, 8));
      mnew[r] = fmaxf(mrow[r], v);
      alpha[r] = exp2f(mrow[r] - mnew[r]);
      mrow[r] = mnew[r];
    }

    float psum[4] = {0.f, 0.f, 0.f, 0.f};
#pragma unroll
    for (int nt = 0; nt < 4; ++nt)
#pragma unroll
      for (int r = 0; r < 4; ++r) {
        float p = exp2f(xs[nt][r] - mnew[r]);
        psum[r] += p;
        Plw[(quad * 4 + r) * LSTR + nt * 16 + m] = __float2bfloat16(p);
      }
#pragma unroll
    for (int r = 0; r < 4; ++r) {
      float v = psum[r];
      v += __shfl_xor(v, 1);
      v += __shfl_xor(v, 2);
      v += __shfl_xor(v, 4);
      v += __shfl_xor(v, 8);
      lrow[r] = lrow[r] * alpha[r] + v;
    }
#pragma unroll
    for (int nt = 0; nt < 4; ++nt)
#pragma unroll
      for (int r = 0; r < 4; ++r) Oacc[nt][r] *= alpha[r];

    // O += P V : P A-frags from wave-private LDS; V B-frags from Vl ([h][t])
    bf16x8 pf0 = *(const bf16x8*)(&Plw[m * LSTR + quad * 8]);
    bf16x8 pf1 = *(const bf16x8*)(&Plw[m * LSTR + 32 + quad * 8]);
#pragma unroll
    for (int nt = 0; nt < 4; ++nt) {
      bf16x8 vf0 = *(const bf16x8*)(&Vl[(nt * 16 + m) * LSTR + quad * 8]);
      bf16x8 vf1 = *(const bf16x8*)(&Vl[(nt * 16 + m) * LSTR + 32 + quad * 8]);
      Oacc[nt] = __builtin_amdgcn_mfma_f32_16x16x32_bf16(pf0, vf0, Oacc[nt], 0, 0, 0);
      Oacc[nt] = __builtin_amdgcn_mfma_f32_16x16x32_bf16(pf1, vf1, Oacc[nt], 0, 0, 0);
    }
  }

  float inv[4];
#pragma unroll
  for (int r = 0; r < 4; ++r) inv[r] = 1.f / lrow[r];
#pragma unroll
  for (int nt = 0; nt < 4; ++nt)
#pragma unroll
    for (int r = 0; r < 4; ++r)
      out[((size_t)b * T_ + q0 + wave * 16 + quad * 4 + r) * H_ + nt * 16 + m] =
          Oacc[nt][r] * inv[r];
}

extern "C" void kernel_launch(void* const* d_in, const int* in_sizes, int n_in,
                              void* d_out, int out_size, void* d_ws, size_t ws_size,
                              hipStream_t stream) {
  const float* x = (const float*)d_in[0];
  const float* Wk = (const float*)d_in[1];
  const float* Wq = (const float*)d_in[2];
  const float* Wv = (const float*)d_in[3];
  float* out = (float*)d_out;
  char* ws = (char*)d_ws;
  // ws layout: Wt bf16 [192][1024] | q bf16 [4][4096][64] | k same | vT bf16 [4][64][4096]
  __hip_bfloat16* Wt = (__hip_bfloat16*)ws;
  __hip_bfloat16* qb = (__hip_bfloat16*)(ws + 393216);
  __hip_bfloat16* kb = (__hip_bfloat16*)(ws + 393216 + 2097152);
  __hip_bfloat16* vT = (__hip_bfloat16*)(ws + 393216 + 2 * 2097152);

  hipLaunchKernelGGL(wtrans_kernel, dim3(768), dim3(256), 0, stream, Wk, Wq, Wv, Wt);
  hipLaunchKernelGGL(proj_kernel, dim3(256), dim3(256), 0, stream, x, Wt, qb, kb, vT);
  hipLaunchKernelGGL(flash_kernel, dim3(64, 4), dim3(256), 0, stream, qb, kb, vT, out);
}

// Round 2
// 245.037 us; speedup vs baseline: 1.1226x; 1.1226x over previous
//
#include <hip/hip_runtime.h>
#include <hip/hip_bf16.h>

#define T_ 4096
#define C_ 1024
#define H_ 64
#define LSTR 72  // P-buffer LDS row stride: mult-of-8 keeps 16B alignment, breaks pow2 banks

typedef short bf16x8 __attribute__((ext_vector_type(8)));
typedef float f32x4 __attribute__((ext_vector_type(4)));

__device__ __forceinline__ short f2bf(float f) {
  union { __hip_bfloat16 h; short s; } u;
  u.h = __float2bfloat16(f);
  return u.s;
}

// ---- kernel 0: W[c][h] fp32 -> Wt[n][c] bf16, n in [0,192): 0-63=K, 64-127=Q, 128-191=V
__global__ void wtrans_kernel(const float* __restrict__ Wk,
                              const float* __restrict__ Wq,
                              const float* __restrict__ Wv,
                              __hip_bfloat16* __restrict__ Wt) {
  int tid = blockIdx.x * 256 + threadIdx.x;
  if (tid >= 192 * 1024) return;
  int n = tid >> 10;
  int c = tid & 1023;
  const float* W = (n < 64) ? Wk : ((n < 128) ? Wq : Wv);
  Wt[tid] = __float2bfloat16(W[c * 64 + (n & 63)]);
}

// ---- kernel 1: qkv projection. 3072 wave-jobs: (rowtile16 x {K,Q,V}). Barrier-free.
__global__ __launch_bounds__(256) void proj_kernel(
    const float* __restrict__ x, const __hip_bfloat16* __restrict__ Wt,
    __hip_bfloat16* __restrict__ qb, __hip_bfloat16* __restrict__ kb,
    __hip_bfloat16* __restrict__ vT) {
  __shared__ __hip_bfloat16 vlds[4][64 * 16];
  const int lane = threadIdx.x & 63;
  const int wave = threadIdx.x >> 6;
  const int m = lane & 15;
  const int quad = lane >> 4;
  const int jid = blockIdx.x * 4 + wave;   // 0..3071
  const int rt = jid / 3;                  // row tile 0..1023
  const int which = jid - rt * 3;          // 0=K 1=Q 2=V
  const int t0 = rt * 16;

  f32x4 acc[4];
#pragma unroll
  for (int i = 0; i < 4; ++i) acc[i] = (f32x4){0.f, 0.f, 0.f, 0.f};

  const float* xrow = x + (size_t)(t0 + m) * C_ + quad * 8;
  const __hip_bfloat16* wrow = Wt + ((size_t)which * 64 + m) * C_ + quad * 8;

  for (int kc = 0; kc < C_; kc += 32) {
    float4 xa = *(const float4*)(xrow + kc);
    float4 xb = *(const float4*)(xrow + kc + 4);
    bf16x8 a;
    a[0] = f2bf(xa.x); a[1] = f2bf(xa.y); a[2] = f2bf(xa.z); a[3] = f2bf(xa.w);
    a[4] = f2bf(xb.x); a[5] = f2bf(xb.y); a[6] = f2bf(xb.z); a[7] = f2bf(xb.w);
#pragma unroll
    for (int nt = 0; nt < 4; ++nt) {
      bf16x8 bfrag = *(const bf16x8*)(wrow + (size_t)nt * 16 * C_ + kc);
      acc[nt] = __builtin_amdgcn_mfma_f32_16x16x32_bf16(a, bfrag, acc[nt], 0, 0, 0);
    }
  }

  if (which < 2) {
    __hip_bfloat16* dst = (which == 0) ? kb : qb;
#pragma unroll
    for (int nt = 0; nt < 4; ++nt)
#pragma unroll
      for (int r = 0; r < 4; ++r)
        dst[(size_t)(t0 + quad * 4 + r) * H_ + nt * 16 + m] = __float2bfloat16(acc[nt][r]);
  } else {
    // V: transpose to vT[b][h][t] via wave-private LDS (no barrier: same-wave RAW)
    __hip_bfloat16* vl = &vlds[wave][0];
#pragma unroll
    for (int nt = 0; nt < 4; ++nt)
#pragma unroll
      for (int r = 0; r < 4; ++r)
        vl[(nt * 16 + m) * 16 + quad * 4 + r] = __float2bfloat16(acc[nt][r]);
    int bb = t0 >> 12;
    int tl = t0 & (T_ - 1);
    uint4 v0 = *(const uint4*)(vl + lane * 16);
    uint4 v1 = *(const uint4*)(vl + lane * 16 + 8);
    __hip_bfloat16* dst = vT + ((size_t)bb * H_ + lane) * T_ + tl;
    *(uint4*)(dst) = v0;
    *(uint4*)(dst + 8) = v1;
  }
}

// ---- kernel 2: flash pass1, split-KV. 4608 wave-jobs = (b, qtile16, chunk512).
// Barrier-free: K/V frags straight from global (L2-hot), P round-trip in wave-private LDS.
__global__ __launch_bounds__(256, 4) void fa_pass1(
    const __hip_bfloat16* __restrict__ qb, const __hip_bfloat16* __restrict__ kb,
    const __hip_bfloat16* __restrict__ vT, float* __restrict__ Opart,
    float* __restrict__ Ml) {
  __shared__ __hip_bfloat16 Pl[4][16 * LSTR];
  const int lane = threadIdx.x & 63;
  const int wave = threadIdx.x >> 6;
  const int m = lane & 15;
  const int quad = lane >> 4;

  const int jid = blockIdx.x * 4 + wave;  // 0..4607
  const int b = jid / 1152;
  const int j2 = jid - b * 1152;
  int g = 7;
  while (16 * g * (g + 1) > j2) --g;      // qtile group: nc = g+1 chunks
  const int r2 = j2 - 16 * g * (g + 1);
  const int qt = 32 * g + r2 / (g + 1);
  const int c = r2 - (r2 / (g + 1)) * (g + 1);
  const int q0 = qt * 16;
  const int k0s = c * 512;
  const int kend0 = k0s + 512;
  const int kend = (kend0 < q0 + 16) ? kend0 : (q0 + 16);
  const int ntile = (kend - k0s + 63) >> 6;

  const __hip_bfloat16* qbase = qb + ((size_t)b * T_ + q0 + m) * H_;
  bf16x8 qf0 = *(const bf16x8*)(qbase + quad * 8);
  bf16x8 qf1 = *(const bf16x8*)(qbase + 32 + quad * 8);

  f32x4 Oacc[4];
#pragma unroll
  for (int i = 0; i < 4; ++i) Oacc[i] = (f32x4){0.f, 0.f, 0.f, 0.f};
  float mrow[4], lrow[4];
#pragma unroll
  for (int r = 0; r < 4; ++r) { mrow[r] = -__builtin_inff(); lrow[r] = 0.f; }

  const __hip_bfloat16* kg = kb + (size_t)b * T_ * H_;
  const __hip_bfloat16* vg = vT + (size_t)b * H_ * T_;
  const float cscale = 0.18033688011112042f;  // log2(e)/sqrt(64)
  __hip_bfloat16* Plw = &Pl[wave][0];

  for (int it = 0; it < ntile; ++it) {
    const int k0 = k0s + it * 64;

    // S = Q K^T, B-frags straight from kb (row n = kv, k-contiguous)
    f32x4 s[4];
#pragma unroll
    for (int nt = 0; nt < 4; ++nt) s[nt] = (f32x4){0.f, 0.f, 0.f, 0.f};
    const __hip_bfloat16* kp = kg + (size_t)(k0 + m) * H_ + quad * 8;
#pragma unroll
    for (int nt = 0; nt < 4; ++nt) {
      bf16x8 kf0 = *(const bf16x8*)(kp + (size_t)nt * 16 * H_);
      bf16x8 kf1 = *(const bf16x8*)(kp + (size_t)nt * 16 * H_ + 32);
      s[nt] = __builtin_amdgcn_mfma_f32_16x16x32_bf16(qf0, kf0, s[nt], 0, 0, 0);
      s[nt] = __builtin_amdgcn_mfma_f32_16x16x32_bf16(qf1, kf1, s[nt], 0, 0, 0);
    }

    // scale to exp2 domain + causal mask (only the diagonal-crossing tile needs it)
    float xs[4][4];
    const bool needmask = (k0 + 63 > q0);
#pragma unroll
    for (int nt = 0; nt < 4; ++nt)
#pragma unroll
      for (int r = 0; r < 4; ++r) {
        float xv = s[nt][r] * cscale;
        if (needmask && (k0 + nt * 16 + m) > (q0 + quad * 4 + r))
          xv = -__builtin_inff();
        xs[nt][r] = xv;
      }

    float mnew[4], alpha[4];
#pragma unroll
    for (int r = 0; r < 4; ++r) {
      float v = fmaxf(fmaxf(xs[0][r], xs[1][r]), fmaxf(xs[2][r], xs[3][r]));
      v = fmaxf(v, __shfl_xor(v, 1));
      v = fmaxf(v, __shfl_xor(v, 2));
      v = fmaxf(v, __shfl_xor(v, 4));
      v = fmaxf(v, __shfl_xor(v, 8));
      mnew[r] = fmaxf(mrow[r], v);
      alpha[r] = exp2f(mrow[r] - mnew[r]);
      mrow[r] = mnew[r];
    }

    float psum[4] = {0.f, 0.f, 0.f, 0.f};
#pragma unroll
    for (int nt = 0; nt < 4; ++nt)
#pragma unroll
      for (int r = 0; r < 4; ++r) {
        float p = exp2f(xs[nt][r] - mnew[r]);
        psum[r] += p;
        Plw[(quad * 4 + r) * LSTR + nt * 16 + m] = __float2bfloat16(p);
      }
#pragma unroll
    for (int r = 0; r < 4; ++r) {
      float v = psum[r];
      v += __shfl_xor(v, 1);
      v += __shfl_xor(v, 2);
      v += __shfl_xor(v, 4);
      v += __shfl_xor(v, 8);
      lrow[r] = lrow[r] * alpha[r] + v;
    }
#pragma unroll
    for (int nt = 0; nt < 4; ++nt)
#pragma unroll
      for (int r = 0; r < 4; ++r) Oacc[nt][r] *= alpha[r];

    // O += P V, V B-frags straight from vT[b][h][t]
    bf16x8 pf0 = *(const bf16x8*)(&Plw[m * LSTR + quad * 8]);
    bf16x8 pf1 = *(const bf16x8*)(&Plw[m * LSTR + 32 + quad * 8]);
    const __hip_bfloat16* vp = vg + (size_t)m * T_ + k0 + quad * 8;
#pragma unroll
    for (int nt = 0; nt < 4; ++nt) {
      bf16x8 vf0 = *(const bf16x8*)(vp + (size_t)nt * 16 * T_);
      bf16x8 vf1 = *(const bf16x8*)(vp + (size_t)nt * 16 * T_ + 32);
      Oacc[nt] = __builtin_amdgcn_mfma_f32_16x16x32_bf16(pf0, vf0, Oacc[nt], 0, 0, 0);
      Oacc[nt] = __builtin_amdgcn_mfma_f32_16x16x32_bf16(pf1, vf1, Oacc[nt], 0, 0, 0);
    }
  }

  float* Op = Opart + (size_t)jid * 1024;
#pragma unroll
  for (int nt = 0; nt < 4; ++nt)
#pragma unroll
    for (int r = 0; r < 4; ++r)
      Op[(quad * 4 + r) * 64 + nt * 16 + m] = Oacc[nt][r];
  if (m == 0) {
#pragma unroll
    for (int r = 0; r < 4; ++r) {
      Ml[(size_t)jid * 32 + quad * 4 + r] = mrow[r];
      Ml[(size_t)jid * 32 + 16 + quad * 4 + r] = lrow[r];
    }
  }
}

// ---- kernel 3: combine partials. 1024 WGs = (b, qtile16); thread = (row, 4 h's).
__global__ __launch_bounds__(256) void fa_combine(
    const float* __restrict__ Opart, const float* __restrict__ Ml,
    float* __restrict__ out) {
  const int bq = blockIdx.x;
  const int b = bq >> 8;
  const int qt = bq & 255;
  const int g = qt >> 5;
  const int nc = g + 1;
  const int jbase = b * 1152 + 16 * g * (g + 1) + (qt & 31) * nc;
  const int r = threadIdx.x >> 4;
  const int h0 = (threadIdx.x & 15) * 4;

  float M = -__builtin_inff();
  for (int c = 0; c < nc; ++c) {
    float mv = Ml[(size_t)(jbase + c) * 32 + r];
    M = fmaxf(M, mv);
  }
  float4 O = {0.f, 0.f, 0.f, 0.f};
  float L = 0.f;
  for (int c = 0; c < nc; ++c) {
    float mv = Ml[(size_t)(jbase + c) * 32 + r];
    float lv = Ml[(size_t)(jbase + c) * 32 + 16 + r];
    float w = exp2f(mv - M);
    float4 o = *(const float4*)(Opart + (size_t)(jbase + c) * 1024 + r * 64 + h0);
    O.x += w * o.x; O.y += w * o.y; O.z += w * o.z; O.w += w * o.w;
    L += w * lv;
  }
  float inv = 1.f / L;
  float4 res = {O.x * inv, O.y * inv, O.z * inv, O.w * inv};
  *(float4*)(out + ((size_t)b * T_ + qt * 16 + r) * H_ + h0) = res;
}

extern "C" void kernel_launch(void* const* d_in, const int* in_sizes, int n_in,
                              void* d_out, int out_size, void* d_ws, size_t ws_size,
                              hipStream_t stream) {
  const float* x = (const float*)d_in[0];
  const float* Wk = (const float*)d_in[1];
  const float* Wq = (const float*)d_in[2];
  const float* Wv = (const float*)d_in[3];
  float* out = (float*)d_out;
  char* ws = (char*)d_ws;
  // ws: Wt[192][1024]bf16 | qb[4][4096][64]bf16 | kb same | vT[4][64][4096]bf16
  //     | Opart[4608][16][64]f32 | Ml[4608][2][16]f32   (total ~25 MB)
  __hip_bfloat16* Wt = (__hip_bfloat16*)ws;
  __hip_bfloat16* qb = (__hip_bfloat16*)(ws + 393216);
  __hip_bfloat16* kb = (__hip_bfloat16*)(ws + 2490368);
  __hip_bfloat16* vT = (__hip_bfloat16*)(ws + 4587520);
  float* Opart = (float*)(ws + 6684672);
  float* Ml = (float*)(ws + 25559040);

  hipLaunchKernelGGL(wtrans_kernel, dim3(768), dim3(256), 0, stream, Wk, Wq, Wv, Wt);
  hipLaunchKernelGGL(proj_kernel, dim3(768), dim3(256), 0, stream, x, Wt, qb, kb, vT);
  hipLaunchKernelGGL(fa_pass1, dim3(1152), dim3(256), 0, stream, qb, kb, vT, Opart, Ml);
  hipLaunchKernelGGL(fa_combine, dim3(1024), dim3(256), 0, stream, Opart, Ml, out);
}

// Round 3
// 202.503 us; speedup vs baseline: 1.3584x; 1.2100x over previous
//
#include <hip/hip_runtime.h>
#include <hip/hip_bf16.h>

#define T_ 4096
#define C_ 1024
#define H_ 64
#define LSTR 72  // P-buffer LDS row stride: mult-of-8 keeps 16B alignment, breaks pow2 banks

typedef short bf16x8 __attribute__((ext_vector_type(8)));
typedef float f32x4 __attribute__((ext_vector_type(4)));

__device__ __forceinline__ short f2bf(float f) {
  union { __hip_bfloat16 h; short s; } u;
  u.h = __float2bfloat16(f);
  return u.s;
}

// ---- kernel 0: W[c][h] fp32 -> Wt[n][c] bf16, n in [0,192): 0-63=K, 64-127=Q, 128-191=V
__global__ void wtrans_kernel(const float* __restrict__ Wk,
                              const float* __restrict__ Wq,
                              const float* __restrict__ Wv,
                              __hip_bfloat16* __restrict__ Wt) {
  int tid = blockIdx.x * 256 + threadIdx.x;
  if (tid >= 192 * 1024) return;
  int n = tid >> 10;
  int c = tid & 1023;
  const float* W = (n < 64) ? Wk : ((n < 128) ? Wq : Wv);
  Wt[tid] = __float2bfloat16(W[c * 64 + (n & 63)]);
}

// ---- kernel 1: qkv projection. 3072 wave-jobs: (rowtile16 x {K,Q,V}). Barrier-free.
// K and V are written in MFMA-FRAGMENT ORDER so fa_pass1's loads are lane-contiguous:
//   Kf[b][ktile][inst=(nt*2+which)][lane][j]  elem (kv,h): nt=kvo>>4, m=kvo&15,
//        which=h>>5, quad=(h>>3)&3, j=h&7, lane=quad*16+m
//   Vf[b][ktile][inst=(nt*2+half)][lane][j]   elem (kv,h): half=(kvo>>5), quad=(kvo>>3)&3,
//        j=kvo&7, nt=h>>4, m=h&15, lane=quad*16+m
__global__ __launch_bounds__(256) void proj_kernel(
    const float* __restrict__ x, const __hip_bfloat16* __restrict__ Wt,
    __hip_bfloat16* __restrict__ qb, __hip_bfloat16* __restrict__ Kf,
    __hip_bfloat16* __restrict__ Vf) {
  const int lane = threadIdx.x & 63;
  const int wave = threadIdx.x >> 6;
  const int m = lane & 15;
  const int quad = lane >> 4;
  const int jid = blockIdx.x * 4 + wave;   // 0..3071
  const int rt = jid / 3;                  // row tile 0..1023
  const int which = jid - rt * 3;          // 0=K 1=Q 2=V
  const int t0 = rt * 16;

  f32x4 acc[4];
#pragma unroll
  for (int i = 0; i < 4; ++i) acc[i] = (f32x4){0.f, 0.f, 0.f, 0.f};

  const float* xrow = x + (size_t)(t0 + m) * C_ + quad * 8;
  const __hip_bfloat16* wrow = Wt + ((size_t)which * 64 + m) * C_ + quad * 8;

  float4 xa = *(const float4*)(xrow);
  float4 xb = *(const float4*)(xrow + 4);
  for (int kc = 0; kc < C_; kc += 32) {
    float4 na, nb;
    if (kc + 32 < C_) {  // software pipeline: next x loads in flight during MFMAs
      na = *(const float4*)(xrow + kc + 32);
      nb = *(const float4*)(xrow + kc + 36);
    }
    bf16x8 a;
    a[0] = f2bf(xa.x); a[1] = f2bf(xa.y); a[2] = f2bf(xa.z); a[3] = f2bf(xa.w);
    a[4] = f2bf(xb.x); a[5] = f2bf(xb.y); a[6] = f2bf(xb.z); a[7] = f2bf(xb.w);
#pragma unroll
    for (int nt = 0; nt < 4; ++nt) {
      bf16x8 bfrag = *(const bf16x8*)(wrow + (size_t)nt * 16 * C_ + kc);
      acc[nt] = __builtin_amdgcn_mfma_f32_16x16x32_bf16(a, bfrag, acc[nt], 0, 0, 0);
    }
    xa = na; xb = nb;
  }

  const int bb = t0 >> 12;
  const int tloc = t0 & (T_ - 1);
  const int ktile = tloc >> 6;

  if (which == 1) {  // Q: row-major [t][h], read once per wave in pass1
#pragma unroll
    for (int nt = 0; nt < 4; ++nt)
#pragma unroll
      for (int r = 0; r < 4; ++r)
        qb[(size_t)(t0 + quad * 4 + r) * H_ + nt * 16 + m] = __float2bfloat16(acc[nt][r]);
  } else if (which == 0) {  // K -> frag order
    __hip_bfloat16* dst = Kf + ((size_t)bb * 64 + ktile) * 4096;
    const int ntK = (tloc >> 4) & 3;
#pragma unroll
    for (int nt = 0; nt < 4; ++nt) {
      const int wh = nt >> 1;                       // h>>5
      const int quadK = (nt * 2 + (m >> 3)) & 3;    // (h>>3)&3
      const int j = m & 7;
#pragma unroll
      for (int r = 0; r < 4; ++r) {
        const int mK = quad * 4 + r;                // kvo&15
        dst[(ntK * 2 + wh) * 512 + (quadK * 16 + mK) * 8 + j] = __float2bfloat16(acc[nt][r]);
      }
    }
  } else {  // V -> frag order
    __hip_bfloat16* dst = Vf + ((size_t)bb * 64 + ktile) * 4096;
#pragma unroll
    for (int nt = 0; nt < 4; ++nt) {
#pragma unroll
      for (int r = 0; r < 4; ++r) {
        const int kvo = (tloc & 63) + quad * 4 + r;
        const int half = (kvo >> 5) & 1;
        const int quadV = (kvo >> 3) & 3;
        const int j = kvo & 7;
        dst[(nt * 2 + half) * 512 + (quadV * 16 + m) * 8 + j] = __float2bfloat16(acc[nt][r]);
      }
    }
  }
}

// ---- kernel 2: flash pass1, split-KV. 4608 wave-jobs = (b, qtile16, chunk512).
// All K/V frag loads are lane*16B coalesced bursts from the pre-swizzled Kf/Vf.
__global__ __launch_bounds__(256, 4) void fa_pass1(
    const __hip_bfloat16* __restrict__ qb, const __hip_bfloat16* __restrict__ Kf,
    const __hip_bfloat16* __restrict__ Vf, float* __restrict__ Opart,
    float* __restrict__ Ml) {
  __shared__ __hip_bfloat16 Pl[4][16 * LSTR];
  const int lane = threadIdx.x & 63;
  const int wave = threadIdx.x >> 6;
  const int m = lane & 15;
  const int quad = lane >> 4;

  const int jid = blockIdx.x * 4 + wave;  // 0..4607
  const int b = jid / 1152;
  const int j2 = jid - b * 1152;
  int g = 7;
  while (16 * g * (g + 1) > j2) --g;      // qtile group: nc = g+1 chunks
  const int r2 = j2 - 16 * g * (g + 1);
  const int qt = 32 * g + r2 / (g + 1);
  const int c = r2 - (r2 / (g + 1)) * (g + 1);
  const int q0 = qt * 16;
  const int k0s = c * 512;
  const int kend0 = k0s + 512;
  const int kend = (kend0 < q0 + 16) ? kend0 : (q0 + 16);
  const int ntile = (kend - k0s + 63) >> 6;

  const __hip_bfloat16* qbase = qb + ((size_t)b * T_ + q0 + m) * H_;
  bf16x8 qf0 = *(const bf16x8*)(qbase + quad * 8);
  bf16x8 qf1 = *(const bf16x8*)(qbase + 32 + quad * 8);

  f32x4 Oacc[4];
#pragma unroll
  for (int i = 0; i < 4; ++i) Oacc[i] = (f32x4){0.f, 0.f, 0.f, 0.f};
  float mrow[4], lrow[4];
#pragma unroll
  for (int r = 0; r < 4; ++r) { mrow[r] = -__builtin_inff(); lrow[r] = 0.f; }

  const __hip_bfloat16* kgf = Kf + (size_t)b * 262144 + lane * 8;
  const __hip_bfloat16* vgf = Vf + (size_t)b * 262144 + lane * 8;
  const float cscale = 0.18033688011112042f;  // log2(e)/sqrt(64)
  __hip_bfloat16* Plw = &Pl[wave][0];

  for (int it = 0; it < ntile; ++it) {
    const int ktile = (k0s >> 6) + it;
    const int k0 = ktile * 64;
    const __hip_bfloat16* kp = kgf + (size_t)ktile * 4096;
    const __hip_bfloat16* vp = vgf + (size_t)ktile * 4096;

    // S = Q K^T — coalesced frag loads
    f32x4 s[4];
#pragma unroll
    for (int nt = 0; nt < 4; ++nt) {
      bf16x8 kf0 = *(const bf16x8*)(kp + nt * 1024);
      bf16x8 kf1 = *(const bf16x8*)(kp + nt * 1024 + 512);
      f32x4 t = (f32x4){0.f, 0.f, 0.f, 0.f};
      t = __builtin_amdgcn_mfma_f32_16x16x32_bf16(qf0, kf0, t, 0, 0, 0);
      t = __builtin_amdgcn_mfma_f32_16x16x32_bf16(qf1, kf1, t, 0, 0, 0);
      s[nt] = t;
    }

    // V frags issued NOW (no data dependency): latency hides under softmax
    bf16x8 vf[8];
#pragma unroll
    for (int nt = 0; nt < 4; ++nt) {
      vf[2 * nt] = *(const bf16x8*)(vp + nt * 1024);
      vf[2 * nt + 1] = *(const bf16x8*)(vp + nt * 1024 + 512);
    }

    // scale to exp2 domain + causal mask (only diagonal-crossing tile)
    float xs[4][4];
    const bool needmask = (k0 + 63 > q0);
#pragma unroll
    for (int nt = 0; nt < 4; ++nt)
#pragma unroll
      for (int r = 0; r < 4; ++r) {
        float xv = s[nt][r] * cscale;
        if (needmask && (k0 + nt * 16 + m) > (q0 + quad * 4 + r))
          xv = -__builtin_inff();
        xs[nt][r] = xv;
      }

    float mnew[4], alpha[4];
#pragma unroll
    for (int r = 0; r < 4; ++r) {
      float v = fmaxf(fmaxf(xs[0][r], xs[1][r]), fmaxf(xs[2][r], xs[3][r]));
      v = fmaxf(v, __shfl_xor(v, 1));
      v = fmaxf(v, __shfl_xor(v, 2));
      v = fmaxf(v, __shfl_xor(v, 4));
      v = fmaxf(v, __shfl_xor(v, 8));
      mnew[r] = fmaxf(mrow[r], v);
      alpha[r] = exp2f(mrow[r] - mnew[r]);
      mrow[r] = mnew[r];
    }

    float psum[4] = {0.f, 0.f, 0.f, 0.f};
#pragma unroll
    for (int nt = 0; nt < 4; ++nt)
#pragma unroll
      for (int r = 0; r < 4; ++r) {
        float p = exp2f(xs[nt][r] - mnew[r]);
        psum[r] += p;
        Plw[(quad * 4 + r) * LSTR + nt * 16 + m] = __float2bfloat16(p);
      }
#pragma unroll
    for (int r = 0; r < 4; ++r) {
      float v = psum[r];
      v += __shfl_xor(v, 1);
      v += __shfl_xor(v, 2);
      v += __shfl_xor(v, 4);
      v += __shfl_xor(v, 8);
      lrow[r] = lrow[r] * alpha[r] + v;
    }
#pragma unroll
    for (int nt = 0; nt < 4; ++nt)
#pragma unroll
      for (int r = 0; r < 4; ++r) Oacc[nt][r] *= alpha[r];

    // O += P V
    bf16x8 pf0 = *(const bf16x8*)(&Plw[m * LSTR + quad * 8]);
    bf16x8 pf1 = *(const bf16x8*)(&Plw[m * LSTR + 32 + quad * 8]);
#pragma unroll
    for (int nt = 0; nt < 4; ++nt) {
      Oacc[nt] = __builtin_amdgcn_mfma_f32_16x16x32_bf16(pf0, vf[2 * nt], Oacc[nt], 0, 0, 0);
      Oacc[nt] = __builtin_amdgcn_mfma_f32_16x16x32_bf16(pf1, vf[2 * nt + 1], Oacc[nt], 0, 0, 0);
    }
  }

  float* Op = Opart + (size_t)jid * 1024;
#pragma unroll
  for (int nt = 0; nt < 4; ++nt)
#pragma unroll
    for (int r = 0; r < 4; ++r)
      Op[(quad * 4 + r) * 64 + nt * 16 + m] = Oacc[nt][r];
  if (m == 0) {
#pragma unroll
    for (int r = 0; r < 4; ++r) {
      Ml[(size_t)jid * 32 + quad * 4 + r] = mrow[r];
      Ml[(size_t)jid * 32 + 16 + quad * 4 + r] = lrow[r];
    }
  }
}

// ---- kernel 3: combine partials. 1024 WGs = (b, qtile16); thread = (row, 4 h's).
__global__ __launch_bounds__(256) void fa_combine(
    const float* __restrict__ Opart, const float* __restrict__ Ml,
    float* __restrict__ out) {
  const int bq = blockIdx.x;
  const int b = bq >> 8;
  const int qt = bq & 255;
  const int g = qt >> 5;
  const int nc = g + 1;
  const int jbase = b * 1152 + 16 * g * (g + 1) + (qt & 31) * nc;
  const int r = threadIdx.x >> 4;
  const int h0 = (threadIdx.x & 15) * 4;

  float M = -__builtin_inff();
  for (int c = 0; c < nc; ++c) {
    float mv = Ml[(size_t)(jbase + c) * 32 + r];
    M = fmaxf(M, mv);
  }
  float4 O = {0.f, 0.f, 0.f, 0.f};
  float L = 0.f;
  for (int c = 0; c < nc; ++c) {
    float mv = Ml[(size_t)(jbase + c) * 32 + r];
    float lv = Ml[(size_t)(jbase + c) * 32 + 16 + r];
    float w = exp2f(mv - M);
    float4 o = *(const float4*)(Opart + (size_t)(jbase + c) * 1024 + r * 64 + h0);
    O.x += w * o.x; O.y += w * o.y; O.z += w * o.z; O.w += w * o.w;
    L += w * lv;
  }
  float inv = 1.f / L;
  float4 res = {O.x * inv, O.y * inv, O.z * inv, O.w * inv};
  *(float4*)(out + ((size_t)b * T_ + qt * 16 + r) * H_ + h0) = res;
}

extern "C" void kernel_launch(void* const* d_in, const int* in_sizes, int n_in,
                              void* d_out, int out_size, void* d_ws, size_t ws_size,
                              hipStream_t stream) {
  const float* x = (const float*)d_in[0];
  const float* Wk = (const float*)d_in[1];
  const float* Wq = (const float*)d_in[2];
  const float* Wv = (const float*)d_in[3];
  float* out = (float*)d_out;
  char* ws = (char*)d_ws;
  // ws: Wt[192][1024]bf16 | qb[4][4096][64]bf16 | Kf[4][64][4096]bf16(frag order)
  //     | Vf same | Opart[4608][16][64]f32 | Ml[4608][2][16]f32   (~26.1 MB, same as R2)
  __hip_bfloat16* Wt = (__hip_bfloat16*)ws;
  __hip_bfloat16* qb = (__hip_bfloat16*)(ws + 393216);
  __hip_bfloat16* Kf = (__hip_bfloat16*)(ws + 2490368);
  __hip_bfloat16* Vf = (__hip_bfloat16*)(ws + 4587520);
  float* Opart = (float*)(ws + 6684672);
  float* Ml = (float*)(ws + 25559040);

  hipLaunchKernelGGL(wtrans_kernel, dim3(768), dim3(256), 0, stream, Wk, Wq, Wv, Wt);
  hipLaunchKernelGGL(proj_kernel, dim3(768), dim3(256), 0, stream, x, Wt, qb, Kf, Vf);
  hipLaunchKernelGGL(fa_pass1, dim3(1152), dim3(256), 0, stream, qb, Kf, Vf, Opart, Ml);
  hipLaunchKernelGGL(fa_combine, dim3(1024), dim3(256), 0, stream, Opart, Ml, out);
}